// Round 1
// baseline (13880.162 us; speedup 1.0000x reference)
//
#include <hip/hip_runtime.h>

// C3-style layer: 16 output channels, each a 5x5 VALID conv over a subset of
// the 6 input channels. x[32,6,512,512] f32 -> out[32,16,508,508] f32.
//
// Channel subsets (compile-time):
//   oc 0..5  use CH3[oc]   (3 ics), weights w3[6,3,5,5],  bias b3[6]
//   oc 6..14 use CH4[oc-6] (4 ics), weights w4[9,4,5,5],  bias b4[9]
//   oc 15    uses all 6,            weights w6[1,6,5,5],  bias b6[1]
// Each ic feeds exactly 10 ocs -> OCL[ic][10] below.

#define OW 508
#define TILE 32
#define HALO 36   // TILE + 4

__device__ __constant__ int d_CH3[6][3] = {
    {0,1,2},{1,2,3},{2,3,4},{3,4,5},{0,4,5},{0,1,5}};
__device__ __constant__ int d_CH4[9][4] = {
    {0,1,2,3},{1,2,3,4},{2,3,4,5},{0,3,4,5},{0,1,4,5},
    {0,1,2,5},{0,1,3,4},{1,2,4,5},{0,2,3,5}};

// OCL[ic][j]: the 10 output channels that consume input channel ic.
__device__ __constant__ int d_OCL[6][10] = {
    {0,4,5,6,9,10,11,12,14,15},
    {0,1,5,6,7,10,11,12,13,15},
    {0,1,2,6,7,8,11,13,14,15},
    {1,2,3,6,7,8,9,12,14,15},
    {2,3,4,7,8,9,10,12,13,15},
    {3,4,5,8,9,10,11,13,14,15}};

// Build Wd[ic][ky][j(0..9)][kx(0..4)] (1500 f32) + bias[16] into workspace.
__global__ void prep_weights(const float* __restrict__ w3, const float* __restrict__ b3,
                             const float* __restrict__ w4, const float* __restrict__ b4,
                             const float* __restrict__ w6, const float* __restrict__ b6,
                             float* __restrict__ Wd, float* __restrict__ bias) {
    __shared__ float Wfull[16 * 6 * 25];   // dense [oc][ic][tap], zeros elsewhere
    const int tid = threadIdx.x;
    for (int i = tid; i < 16 * 6 * 25; i += 256) Wfull[i] = 0.f;
    __syncthreads();
    // scatter w3: [6,3,25]
    for (int i = tid; i < 6 * 3 * 25; i += 256) {
        int oc = i / 75, r = i % 75, c = r / 25, t = r % 25;
        int ic = d_CH3[oc][c];
        Wfull[(oc * 6 + ic) * 25 + t] = w3[i];
    }
    // scatter w4: [9,4,25]
    for (int i = tid; i < 9 * 4 * 25; i += 256) {
        int o = i / 100, r = i % 100, c = r / 25, t = r % 25;
        int ic = d_CH4[o][c];
        Wfull[((6 + o) * 6 + ic) * 25 + t] = w4[i];
    }
    // scatter w6: [1,6,25] -> oc 15 contiguous
    for (int i = tid; i < 6 * 25; i += 256) {
        Wfull[15 * 150 + i] = w6[i];
    }
    __syncthreads();
    // pack Wd[ic][ky][j][kx]
    for (int i = tid; i < 6 * 5 * 10 * 5; i += 256) {
        int kx = i % 5, j = (i / 5) % 10, ky = (i / 50) % 5, ic = i / 250;
        int oc = d_OCL[ic][j];
        Wd[i] = Wfull[(oc * 6 + ic) * 25 + ky * 5 + kx];
    }
    if (tid < 6)        bias[tid] = b3[tid];
    else if (tid < 15)  bias[tid] = b4[tid - 6];
    else if (tid == 15) bias[tid] = b6[0];
}

// constexpr mirror of d_OCL for compile-time register indexing in the main loop
__global__ __launch_bounds__(256) void conv_main(
        const float* __restrict__ x, const float* __restrict__ Wd,
        const float* __restrict__ bias, float* __restrict__ out) {
    constexpr int OCL[6][10] = {
        {0,4,5,6,9,10,11,12,14,15},
        {0,1,5,6,7,10,11,12,13,15},
        {0,1,2,6,7,8,11,13,14,15},
        {1,2,3,6,7,8,9,12,14,15},
        {2,3,4,7,8,9,10,12,13,15},
        {3,4,5,8,9,10,11,13,14,15}};

    __shared__ float lds[6][HALO][HALO];   // 31104 B

    const int tid = threadIdx.x;
    const int ox0 = blockIdx.x * TILE;
    const int oy0 = blockIdx.y * TILE;
    const int b   = blockIdx.z;

    // ---- stage input tile (guarded; OOB -> 0, never consumed by valid pixels)
    const float* xb = x + (size_t)b * 6 * 512 * 512;
    for (int i = tid; i < 6 * HALO * HALO; i += 256) {
        int ic  = i / (HALO * HALO);
        int r   = i - ic * (HALO * HALO);
        int row = r / HALO;
        int col = r - row * HALO;
        int gy = oy0 + row, gx = ox0 + col;
        float v = 0.f;
        if (gy < 512 && gx < 512) v = xb[(ic * 512 + gy) * 512 + gx];
        lds[ic][row][col] = v;
    }
    __syncthreads();

    const int tx  = tid & 31;
    const int tyb = tid >> 5;          // 0..7 ; pixel rows tyb + 8*p

    float acc[4][16];
    #pragma unroll
    for (int p = 0; p < 4; ++p)
        #pragma unroll
        for (int o = 0; o < 16; ++o) acc[p][o] = bias[o];

    #pragma unroll
    for (int ic = 0; ic < 6; ++ic) {           // compile-time (acc indexing)
        for (int ky = 0; ky < 5; ++ky) {       // runtime loop (I$ friendly)
            // 50 wave-uniform weights for this (ic,ky): [j][kx]
            float wl[50];
            #pragma unroll
            for (int t = 0; t < 50; ++t) wl[t] = Wd[(ic * 5 + ky) * 50 + t];
            #pragma unroll
            for (int p = 0; p < 4; ++p) {
                const int row = tyb + 8 * p + ky;
                float v[5];
                #pragma unroll
                for (int kx = 0; kx < 5; ++kx) v[kx] = lds[ic][row][tx + kx];
                #pragma unroll
                for (int j = 0; j < 10; ++j) {
                    const int oc = OCL[ic][j];
                    #pragma unroll
                    for (int kx = 0; kx < 5; ++kx)
                        acc[p][oc] = fmaf(v[kx], wl[j * 5 + kx], acc[p][oc]);
                }
            }
        }
    }

    // ---- store
    const int ox = ox0 + tx;
    if (ox < OW) {
        #pragma unroll
        for (int p = 0; p < 4; ++p) {
            const int oy = oy0 + tyb + 8 * p;
            if (oy < OW) {
                #pragma unroll
                for (int o = 0; o < 16; ++o)
                    out[(((size_t)b * 16 + o) * OW + oy) * OW + ox] = acc[p][o];
            }
        }
    }
}

extern "C" void kernel_launch(void* const* d_in, const int* in_sizes, int n_in,
                              void* d_out, int out_size, void* d_ws, size_t ws_size,
                              hipStream_t stream) {
    const float* x  = (const float*)d_in[0];
    const float* w3 = (const float*)d_in[1];
    const float* b3 = (const float*)d_in[2];
    const float* w4 = (const float*)d_in[3];
    const float* b4 = (const float*)d_in[4];
    const float* w6 = (const float*)d_in[5];
    const float* b6 = (const float*)d_in[6];
    float* out = (float*)d_out;

    float* Wd   = (float*)d_ws;          // 1500 f32
    float* bias = Wd + 1500;             // 16 f32

    prep_weights<<<1, 256, 0, stream>>>(w3, b3, w4, b4, w6, b6, Wd, bias);

    dim3 grid((OW + TILE - 1) / TILE, (OW + TILE - 1) / TILE, 32);  // 16,16,32
    conv_main<<<grid, 256, 0, stream>>>(x, Wd, bias, out);
}

// Round 2
// 492.903 us; speedup vs baseline: 28.1600x; 28.1600x over previous
//
#include <hip/hip_runtime.h>

// C3-style layer: 16 output channels, each a 5x5 VALID conv over a subset of
// the 6 input channels. x[32,6,512,512] f32 -> out[32,16,508,508] f32.

#define OW 508
#define TILE 32
#define HALO 36   // TILE + 4

__device__ __constant__ int d_CH3[6][3] = {
    {0,1,2},{1,2,3},{2,3,4},{3,4,5},{0,4,5},{0,1,5}};
__device__ __constant__ int d_CH4[9][4] = {
    {0,1,2,3},{1,2,3,4},{2,3,4,5},{0,3,4,5},{0,1,4,5},
    {0,1,2,5},{0,1,3,4},{1,2,4,5},{0,2,3,5}};

// OCL[ic][j]: the 10 output channels that consume input channel ic.
__device__ __constant__ int d_OCL[6][10] = {
    {0,4,5,6,9,10,11,12,14,15},
    {0,1,5,6,7,10,11,12,13,15},
    {0,1,2,6,7,8,11,13,14,15},
    {1,2,3,6,7,8,9,12,14,15},
    {2,3,4,7,8,9,10,12,13,15},
    {3,4,5,8,9,10,11,13,14,15}};

// Build Wd[ic][ky][j(0..9)][kx(0..4)] (1500 f32) + bias[16] into workspace.
__global__ void prep_weights(const float* __restrict__ w3, const float* __restrict__ b3,
                             const float* __restrict__ w4, const float* __restrict__ b4,
                             const float* __restrict__ w6, const float* __restrict__ b6,
                             float* __restrict__ Wd, float* __restrict__ bias) {
    __shared__ float Wfull[16 * 6 * 25];   // dense [oc][ic][tap], zeros elsewhere
    const int tid = threadIdx.x;
    for (int i = tid; i < 16 * 6 * 25; i += 256) Wfull[i] = 0.f;
    __syncthreads();
    for (int i = tid; i < 6 * 3 * 25; i += 256) {          // w3 [6,3,25]
        int oc = i / 75, r = i % 75, c = r / 25, t = r % 25;
        int ic = d_CH3[oc][c];
        Wfull[(oc * 6 + ic) * 25 + t] = w3[i];
    }
    for (int i = tid; i < 9 * 4 * 25; i += 256) {          // w4 [9,4,25]
        int o = i / 100, r = i % 100, c = r / 25, t = r % 25;
        int ic = d_CH4[o][c];
        Wfull[((6 + o) * 6 + ic) * 25 + t] = w4[i];
    }
    for (int i = tid; i < 6 * 25; i += 256) {              // w6 -> oc 15
        Wfull[15 * 150 + i] = w6[i];
    }
    __syncthreads();
    // pack Wd[ic][ky][j][kx]
    for (int i = tid; i < 6 * 5 * 10 * 5; i += 256) {
        int kx = i % 5, j = (i / 5) % 10, ky = (i / 50) % 5, ic = i / 250;
        int oc = d_OCL[ic][j];
        Wd[i] = Wfull[(oc * 6 + ic) * 25 + ky * 5 + kx];
    }
    if (tid < 6)        bias[tid] = b3[tid];
    else if (tid < 15)  bias[tid] = b4[tid - 6];
    else if (tid == 15) bias[tid] = b6[0];
}

__global__ __launch_bounds__(256) void conv_main(
        const float* __restrict__ x, const float* __restrict__ Wd,
        const float* __restrict__ bias, float* __restrict__ out) {
    constexpr int OCL[6][10] = {
        {0,4,5,6,9,10,11,12,14,15},
        {0,1,5,6,7,10,11,12,13,15},
        {0,1,2,6,7,8,11,13,14,15},
        {1,2,3,6,7,8,9,12,14,15},
        {2,3,4,7,8,9,10,12,13,15},
        {3,4,5,8,9,10,11,13,14,15}};

    __shared__ float lds[6][HALO][HALO];   // 31104 B

    const int tid = threadIdx.x;
    const int ox0 = blockIdx.x * TILE;
    const int oy0 = blockIdx.y * TILE;
    const int b   = blockIdx.z;

    // ---- stage input tile (guarded; OOB -> 0, never consumed by valid pixels)
    const float* xb = x + (size_t)b * 6 * 512 * 512;
    for (int i = tid; i < 6 * HALO * HALO; i += 256) {
        int ic  = i / (HALO * HALO);
        int r   = i - ic * (HALO * HALO);
        int row = r / HALO;
        int col = r - row * HALO;
        int gy = oy0 + row, gx = ox0 + col;
        float v = 0.f;
        if (gy < 512 && gx < 512) v = xb[(ic * 512 + gy) * 512 + gx];
        lds[ic][row][col] = v;
    }
    __syncthreads();

    const int tx  = tid & 31;
    const int tyb = tid >> 5;          // 0..7 ; pixel rows tyb + 8*p

    float acc[4][16];
    {
        float bv[16];
        #pragma unroll
        for (int o = 0; o < 16; ++o) bv[o] = bias[o];
        #pragma unroll
        for (int p = 0; p < 4; ++p)
            #pragma unroll
            for (int o = 0; o < 16; ++o) acc[p][o] = bv[o];
    }

    #pragma unroll
    for (int ic = 0; ic < 6; ++ic) {           // compile-time (acc indexing)
        #pragma unroll 1                       // keep ONE ky-slice of weights live
        for (int ky = 0; ky < 5; ++ky) {
            const float* wp = Wd + (ic * 5 + ky) * 50;

            // hoist the 20 LDS input reads; each reused by 10 output channels
            float v[4][5];
            #pragma unroll
            for (int p = 0; p < 4; ++p) {
                const int row = tyb + 8 * p + ky;
                #pragma unroll
                for (int kx = 0; kx < 5; ++kx) v[p][kx] = lds[ic][row][tx + kx];
            }

            #pragma unroll
            for (int j = 0; j < 10; ++j) {
                const int oc = OCL[ic][j];
                // 5-float weight chunk loaded right before its 20 FMAs
                const float w0 = wp[j * 5 + 0];
                const float w1 = wp[j * 5 + 1];
                const float w2 = wp[j * 5 + 2];
                const float w3 = wp[j * 5 + 3];
                const float w4 = wp[j * 5 + 4];
                #pragma unroll
                for (int p = 0; p < 4; ++p) {
                    float a = acc[p][oc];
                    a = fmaf(v[p][0], w0, a);
                    a = fmaf(v[p][1], w1, a);
                    a = fmaf(v[p][2], w2, a);
                    a = fmaf(v[p][3], w3, a);
                    a = fmaf(v[p][4], w4, a);
                    acc[p][oc] = a;
                }
            }
        }
    }

    // ---- store
    const int ox = ox0 + tx;
    if (ox < OW) {
        #pragma unroll
        for (int p = 0; p < 4; ++p) {
            const int oy = oy0 + tyb + 8 * p;
            if (oy < OW) {
                #pragma unroll
                for (int o = 0; o < 16; ++o)
                    out[(((size_t)b * 16 + o) * OW + oy) * OW + ox] = acc[p][o];
            }
        }
    }
}

extern "C" void kernel_launch(void* const* d_in, const int* in_sizes, int n_in,
                              void* d_out, int out_size, void* d_ws, size_t ws_size,
                              hipStream_t stream) {
    const float* x  = (const float*)d_in[0];
    const float* w3 = (const float*)d_in[1];
    const float* b3 = (const float*)d_in[2];
    const float* w4 = (const float*)d_in[3];
    const float* b4 = (const float*)d_in[4];
    const float* w6 = (const float*)d_in[5];
    const float* b6 = (const float*)d_in[6];
    float* out = (float*)d_out;

    float* Wd   = (float*)d_ws;          // 1500 f32
    float* bias = Wd + 1500;             // 16 f32

    prep_weights<<<1, 256, 0, stream>>>(w3, b3, w4, b4, w6, b6, Wd, bias);

    dim3 grid((OW + TILE - 1) / TILE, (OW + TILE - 1) / TILE, 32);  // 16,16,32
    conv_main<<<grid, 256, 0, stream>>>(x, Wd, bias, out);
}

// Round 4
// 331.409 us; speedup vs baseline: 41.8823x; 1.4873x over previous
//
#include <hip/hip_runtime.h>

// C3-style layer: 16 output channels, each a 5x5 VALID conv over a subset of
// the 6 input channels. x[32,6,512,512] f32 -> out[32,16,508,508] f32.
//
// R3: f16 dot2 (v_dot2_f32_f16, f32 accumulate), called UNCONDITIONALLY
// (R2's crash was a host/device __has_builtin divergence -> launched a
// kernel that was never device-compiled). Thread = 2x2 output pixels;
// input staged to LDS as packed f16 pairs; weights pre-packed into
// even/odd shifted f16 pairs so both x-parities use aligned b32 reads.

#define OW 508
#define TILE 32
#define HALO 36   // TILE + 4
#define PITCH 20  // u32 per LDS row: 18 used + 2 pad (bank spread)

typedef _Float16 h2 __attribute__((ext_vector_type(2)));

__device__ __constant__ int d_CH3[6][3] = {
    {0,1,2},{1,2,3},{2,3,4},{3,4,5},{0,4,5},{0,1,5}};
__device__ __constant__ int d_CH4[9][4] = {
    {0,1,2,3},{1,2,3,4},{2,3,4,5},{0,3,4,5},{0,1,4,5},
    {0,1,2,5},{0,1,3,4},{1,2,4,5},{0,2,3,5}};

// OCL[ic][j]: the 10 output channels that consume input channel ic.
__device__ __constant__ int d_OCL[6][10] = {
    {0,4,5,6,9,10,11,12,14,15},
    {0,1,5,6,7,10,11,12,13,15},
    {0,1,2,6,7,8,11,13,14,15},
    {1,2,3,6,7,8,9,12,14,15},
    {2,3,4,7,8,9,10,12,13,15},
    {3,4,5,8,9,10,11,13,14,15}};

// ws layout: bias f32[16] | WP u32[1800]   (total 7328 B)
// WP[((ic*5+ky)*10+j)*6 + dx*3 + t]: f16 pairs
//   dx=0 (even x): (w0,w1),(w2,w3),(w4,0)
//   dx=1 (odd  x): (0,w0),(w1,w2),(w3,w4)
__global__ void prep_weights(const float* __restrict__ w3, const float* __restrict__ b3,
                             const float* __restrict__ w4, const float* __restrict__ b4,
                             const float* __restrict__ w6, const float* __restrict__ b6,
                             float* __restrict__ bias, unsigned int* __restrict__ WP) {
    __shared__ float Wfull[16 * 6 * 25];   // dense [oc][ic][tap]
    const int tid = threadIdx.x;
    for (int i = tid; i < 16 * 6 * 25; i += 256) Wfull[i] = 0.f;
    __syncthreads();
    for (int i = tid; i < 6 * 3 * 25; i += 256) {
        int oc = i / 75, r = i % 75, c = r / 25, t = r % 25;
        Wfull[(oc * 6 + d_CH3[oc][c]) * 25 + t] = w3[i];
    }
    for (int i = tid; i < 9 * 4 * 25; i += 256) {
        int o = i / 100, r = i % 100, c = r / 25, t = r % 25;
        Wfull[((6 + o) * 6 + d_CH4[o][c]) * 25 + t] = w4[i];
    }
    for (int i = tid; i < 6 * 25; i += 256) Wfull[15 * 150 + i] = w6[i];
    __syncthreads();
    // f16 shifted pairs
    for (int i = tid; i < 1800; i += 256) {
        int t = i % 3, dx = (i / 3) % 2, j = (i / 6) % 10, ky = (i / 60) % 5, ic = i / 300;
        const float* w = &Wfull[(d_OCL[ic][j] * 6 + ic) * 25 + ky * 5];
        float lo, hi;
        if (dx == 0) { lo = w[2 * t];                      hi = (2 * t + 1 < 5) ? w[2 * t + 1] : 0.f; }
        else         { lo = (t == 0) ? 0.f : w[2 * t - 1]; hi = w[2 * t]; }
        h2 h; h.x = (_Float16)lo; h.y = (_Float16)hi;
        WP[i] = __builtin_bit_cast(unsigned int, h);
    }
    if (tid < 6)        bias[tid] = b3[tid];
    else if (tid < 15)  bias[tid] = b4[tid - 6];
    else if (tid == 15) bias[tid] = b6[0];
}

__global__ __launch_bounds__(256) void conv_f16(
        const float* __restrict__ x, const unsigned int* __restrict__ WP,
        const float* __restrict__ bias, float* __restrict__ out) {
    constexpr int OCL[6][10] = {
        {0,4,5,6,9,10,11,12,14,15},
        {0,1,5,6,7,10,11,12,13,15},
        {0,1,2,6,7,8,11,13,14,15},
        {1,2,3,6,7,8,9,12,14,15},
        {2,3,4,7,8,9,10,12,13,15},
        {3,4,5,8,9,10,11,13,14,15}};

    __shared__ unsigned int lds[6][HALO][PITCH];   // 17280 B -> 8 blocks/CU

    const int tid = threadIdx.x;
    const int ox0 = blockIdx.x * TILE;
    const int oy0 = blockIdx.y * TILE;
    const int b   = blockIdx.z;

    // ---- stage: f32 global -> f16 pairs in LDS (OOB -> 0)
    const float* xb = x + (size_t)b * 6 * 512 * 512;
    for (int i = tid; i < 6 * HALO * 18; i += 256) {
        int ic  = i / (HALO * 18);
        int r   = i - ic * (HALO * 18);
        int row = r / 18, pr = r - row * 18;
        int gy = oy0 + row, gx = ox0 + 2 * pr;
        float v0 = 0.f, v1 = 0.f;
        if (gy < 512) {
            const float* rp = xb + ((size_t)ic * 512 + gy) * 512;
            if (gx + 1 < 512) { float2 f = *(const float2*)(rp + gx); v0 = f.x; v1 = f.y; }
            else if (gx < 512) v0 = rp[gx];
        }
        h2 h; h.x = (_Float16)v0; h.y = (_Float16)v1;
        lds[ic][row][pr] = __builtin_bit_cast(unsigned int, h);
    }
    __syncthreads();

    const int tx = tid & 15;    // x-pair index: pixels 2tx, 2tx+1
    const int ty = tid >> 4;    // y-pair index: rows  2ty, 2ty+1

    float acc[2][2][16];        // [dy][dx][oc]
    {
        float bv[16];
        #pragma unroll
        for (int o = 0; o < 16; ++o) bv[o] = bias[o];
        #pragma unroll
        for (int dy = 0; dy < 2; ++dy)
            #pragma unroll
            for (int dx = 0; dx < 2; ++dx)
                #pragma unroll
                for (int o = 0; o < 16; ++o) acc[dy][dx][o] = bv[o];
    }

    #pragma unroll
    for (int ic = 0; ic < 6; ++ic) {
        #pragma unroll 1               // ONE 60-word weight slice live (SGPRs)
        for (int ky = 0; ky < 5; ++ky) {
            const unsigned int* wq = WP + (ic * 5 + ky) * 60;
            #pragma unroll
            for (int dy = 0; dy < 2; ++dy) {
                const int row = 2 * ty + dy + ky;
                const unsigned int* lr = &lds[ic][row][tx];
                h2 a0 = __builtin_bit_cast(h2, lr[0]);
                h2 a1 = __builtin_bit_cast(h2, lr[1]);
                h2 a2 = __builtin_bit_cast(h2, lr[2]);
                #pragma unroll
                for (int j = 0; j < 10; ++j) {
                    const int oc = OCL[ic][j];
                    float s = acc[dy][0][oc];
                    s = __builtin_amdgcn_fdot2(a0, __builtin_bit_cast(h2, wq[j * 6 + 0]), s, false);
                    s = __builtin_amdgcn_fdot2(a1, __builtin_bit_cast(h2, wq[j * 6 + 1]), s, false);
                    s = __builtin_amdgcn_fdot2(a2, __builtin_bit_cast(h2, wq[j * 6 + 2]), s, false);
                    acc[dy][0][oc] = s;
                    float u = acc[dy][1][oc];
                    u = __builtin_amdgcn_fdot2(a0, __builtin_bit_cast(h2, wq[j * 6 + 3]), u, false);
                    u = __builtin_amdgcn_fdot2(a1, __builtin_bit_cast(h2, wq[j * 6 + 4]), u, false);
                    u = __builtin_amdgcn_fdot2(a2, __builtin_bit_cast(h2, wq[j * 6 + 5]), u, false);
                    acc[dy][1][oc] = u;
                }
            }
        }
    }

    // ---- store (x-pairs as float2; pair fully in or out since OW is even)
    const int ox = ox0 + 2 * tx;
    if (ox < OW) {
        #pragma unroll
        for (int dy = 0; dy < 2; ++dy) {
            const int oy = oy0 + 2 * ty + dy;
            if (oy < OW) {
                #pragma unroll
                for (int o = 0; o < 16; ++o) {
                    float2 st; st.x = acc[dy][0][o]; st.y = acc[dy][1][o];
                    *(float2*)(&out[(((size_t)b * 16 + o) * OW + oy) * OW + ox]) = st;
                }
            }
        }
    }
}

extern "C" void kernel_launch(void* const* d_in, const int* in_sizes, int n_in,
                              void* d_out, int out_size, void* d_ws, size_t ws_size,
                              hipStream_t stream) {
    const float* x  = (const float*)d_in[0];
    const float* w3 = (const float*)d_in[1];
    const float* b3 = (const float*)d_in[2];
    const float* w4 = (const float*)d_in[3];
    const float* b4 = (const float*)d_in[4];
    const float* w6 = (const float*)d_in[5];
    const float* b6 = (const float*)d_in[6];
    float* out = (float*)d_out;

    float* bias      = (float*)d_ws;                  // 16 f32
    unsigned int* WP = (unsigned int*)d_ws + 16;      // 1800 u32

    prep_weights<<<1, 256, 0, stream>>>(w3, b3, w4, b4, w6, b6, bias, WP);

    dim3 grid((OW + TILE - 1) / TILE, (OW + TILE - 1) / TILE, 32);  // 16,16,32
    conv_f16<<<grid, 256, 0, stream>>>(x, WP, bias, out);
}

// Round 5
// 267.408 us; speedup vs baseline: 51.9062x; 1.2393x over previous
//
#include <hip/hip_runtime.h>

// C3-style layer via MFMA implicit GEMM.
// x[32,6,512,512] f32 -> out[32,16,508,508] f32 (5x5 VALID conv, sparse
// oc<-ic connectivity handled by zero weights in dense [16,6,5,5] kernel).
//
// Decomposition: out[oc, px] = sum_kx sum_{ic,ky} W[oc][ic][ky][kx] * x[ic][py+ky][px+kx]
// For fixed kx this is a GEMM with K = (ky,icp) packed as u = ky*8+icp (icp = ic
// padded to 8).  LDS tile T[col][r][icp] (col pitch 21 uint4): for output row d,
// the K-window is the 16B-aligned slice at uint4 offset +d -> A-fragments are
// d-independent: A[oc,k] = W[oc][ic=k&7][ky=k>>3][kx].  K=64 (2 chunks of 32,
// rows d..d+7, ky>=5 and icp>=6 positions carry zero weights).

#define OW 508
#define BX 64     // output px per block (x);  4 waves x 16-px strips
#define BY 16     // output rows per block
#define TC 68     // T columns = BX + 4
#define TR 21     // uint4 row-slots per column (20 real rows + 1 zero row)
#define TPAD 4    // tail uint4 pad (zeroed) for last-column over-reads

typedef _Float16 h8 __attribute__((ext_vector_type(8)));
typedef _Float16 h2 __attribute__((ext_vector_type(2)));
typedef float f32x4 __attribute__((ext_vector_type(4)));

__device__ __constant__ int d_CH3[6][3] = {
    {0,1,2},{1,2,3},{2,3,4},{3,4,5},{0,4,5},{0,1,5}};
__device__ __constant__ int d_CH4[9][4] = {
    {0,1,2,3},{1,2,3,4},{2,3,4,5},{0,3,4,5},{0,1,4,5},
    {0,1,2,5},{0,1,3,4},{1,2,4,5},{0,2,3,5}};

// ws layout: bias f32[16] | AF ushort[5*2*64*8]  (A-fragments in lane order)
// AF[((kx*2+ch)*64 + lane)*8 + e]: weight for oc=lane&15, ky=ch*4+(lane>>4),
// ic=e, tap kx; zero if ky>=5 or e>=6.
__global__ void prep_weights(const float* __restrict__ w3, const float* __restrict__ b3,
                             const float* __restrict__ w4, const float* __restrict__ b4,
                             const float* __restrict__ w6, const float* __restrict__ b6,
                             float* __restrict__ bias, unsigned short* __restrict__ AF) {
    __shared__ float Wfull[16 * 6 * 25];   // dense [oc][ic][tap]
    const int tid = threadIdx.x;
    for (int i = tid; i < 16 * 6 * 25; i += 256) Wfull[i] = 0.f;
    __syncthreads();
    for (int i = tid; i < 6 * 3 * 25; i += 256) {
        int oc = i / 75, r = i % 75, c = r / 25, t = r % 25;
        Wfull[(oc * 6 + d_CH3[oc][c]) * 25 + t] = w3[i];
    }
    for (int i = tid; i < 9 * 4 * 25; i += 256) {
        int o = i / 100, r = i % 100, c = r / 25, t = r % 25;
        Wfull[((6 + o) * 6 + d_CH4[o][c]) * 25 + t] = w4[i];
    }
    for (int i = tid; i < 6 * 25; i += 256) Wfull[15 * 150 + i] = w6[i];
    __syncthreads();
    // A-fragments
    for (int i = tid; i < 5 * 2 * 64 * 8; i += 256) {
        int e = i & 7, lane = (i >> 3) & 63, ch = (i >> 9) & 1, kx = i >> 10;
        int oc = lane & 15, ky = ch * 4 + (lane >> 4);
        float w = 0.f;
        if (ky < 5 && e < 6) w = Wfull[(oc * 6 + e) * 25 + ky * 5 + kx];
        _Float16 hw = (_Float16)w;
        AF[i] = __builtin_bit_cast(unsigned short, hw);
    }
    if (tid < 6)        bias[tid] = b3[tid];
    else if (tid < 15)  bias[tid] = b4[tid - 6];
    else if (tid == 15) bias[tid] = b6[0];
}

__global__ __launch_bounds__(256) void conv_mfma(
        const float* __restrict__ x, const unsigned short* __restrict__ AF,
        const float* __restrict__ bias, float* __restrict__ out) {
    __shared__ uint4 T4[TC * TR + TPAD];   // 22912 B

    const int tid = threadIdx.x;
    const int gx0 = blockIdx.x * BX;
    const int oy0 = blockIdx.y * BY;
    const int bz  = blockIdx.z;
    const float* xb = x + (size_t)bz * 6 * 512 * 512;

    // ---- stage: T[c][r][icp] as f16; zero for r==20, icp>=6, or OOB.
    // word (c*84 + rr*4 + ip) = f16 pair (ic=2ip, 2ip+1) at (c, rr).
    unsigned int* Tw = (unsigned int*)T4;
    for (int idx = tid; idx < TC * TR * 4 + TPAD * 4; idx += 256) {
        unsigned int val = 0u;
        int waddr = idx;
        if (idx < TC * TR * 4) {
            int c  = idx % TC;
            int rr = (idx / TC) % TR;
            int ip = idx / (TC * TR);      // 0..3 -> ic pair (2ip, 2ip+1)
            waddr = c * 84 + rr * 4 + ip;
            int gy = oy0 + rr, gx = gx0 + c;
            if (ip < 3 && rr < 20 && gy < 512 && gx < 512) {
                const float* p0 = xb + ((size_t)(2 * ip) * 512 + gy) * 512 + gx;
                float v0 = p0[0];
                float v1 = p0[262144];     // next ic plane (512*512)
                h2 h; h.x = (_Float16)v0; h.y = (_Float16)v1;
                val = __builtin_bit_cast(unsigned int, h);
            }
        }
        Tw[waddr] = val;
    }
    __syncthreads();

    const int lane = tid & 63;
    const int n = lane & 15;        // B column = pixel within strip
    const int g = lane >> 4;        // k-group

    // ---- A-fragments: 10 x 16 B per lane, coalesced, L2-resident
    h8 afr[10];
    #pragma unroll
    for (int q = 0; q < 10; ++q)
        afr[q] = *reinterpret_cast<const h8*>(AF + (q * 64 + lane) * 8);

    // bias fragment: acc reg r -> oc = g*4 + r
    f32x4 binit;
    binit.x = bias[g * 4 + 0];
    binit.y = bias[g * 4 + 1];
    binit.z = bias[g * 4 + 2];
    binit.w = bias[g * 4 + 3];

    const int wstrip = tid >> 6;                 // 0..3
    const int col0   = wstrip * 16;
    const int px     = gx0 + col0 + n;           // output x
    const int tbase  = (col0 + n) * TR + g;      // uint4 index base

    #pragma unroll 1
    for (int d = 0; d < BY; ++d) {
        f32x4 acc = binit;
        #pragma unroll
        for (int kx = 0; kx < 5; ++kx) {
            #pragma unroll
            for (int ch = 0; ch < 2; ++ch) {
                h8 b = *reinterpret_cast<const h8*>(&T4[tbase + kx * TR + ch * 4 + d]);
                acc = __builtin_amdgcn_mfma_f32_16x16x32_f16(afr[kx * 2 + ch], b, acc, 0, 0, 0);
            }
        }
        const int oy = oy0 + d;
        if (oy < OW && px < OW) {
            size_t o0 = (((size_t)bz * 16 + g * 4) * OW + oy) * OW + px;
            const size_t cs = (size_t)OW * OW;
            out[o0]          = acc.x;
            out[o0 + cs]     = acc.y;
            out[o0 + 2 * cs] = acc.z;
            out[o0 + 3 * cs] = acc.w;
        }
    }
}

extern "C" void kernel_launch(void* const* d_in, const int* in_sizes, int n_in,
                              void* d_out, int out_size, void* d_ws, size_t ws_size,
                              hipStream_t stream) {
    const float* x  = (const float*)d_in[0];
    const float* w3 = (const float*)d_in[1];
    const float* b3 = (const float*)d_in[2];
    const float* w4 = (const float*)d_in[3];
    const float* b4 = (const float*)d_in[4];
    const float* w6 = (const float*)d_in[5];
    const float* b6 = (const float*)d_in[6];
    float* out = (float*)d_out;

    float* bias        = (float*)d_ws;                    // 16 f32
    unsigned short* AF = (unsigned short*)(bias + 16);    // 5120 u16

    prep_weights<<<1, 256, 0, stream>>>(w3, b3, w4, b4, w6, b6, bias, AF);

    dim3 grid((OW + BX - 1) / BX, (OW + BY - 1) / BY, 32);  // 8, 32, 32
    conv_mfma<<<grid, 256, 0, stream>>>(x, AF, bias, out);
}